// Round 1
// baseline (330.932 us; speedup 1.0000x reference)
//
#include <hip/hip_runtime.h>

#define TTOK 4096
#define NEXP 8
#define DDIM 512
#define FDIM 2048

typedef __attribute__((ext_vector_type(8))) short short8;
typedef __attribute__((ext_vector_type(4))) float floatx4;

__device__ __forceinline__ ushort f2b(float f) {
  unsigned u = __float_as_uint(f);
  u += 0x7fffu + ((u >> 16) & 1u);   // round-to-nearest-even bf16
  return (ushort)(u >> 16);
}

// ---------------- router: logits (f32, exact) + top-2 + softmax + list append
__global__ __launch_bounds__(256) void k_router(
    const float* __restrict__ x, const float* __restrict__ gw,
    float* __restrict__ logits, int* __restrict__ counts,
    int* __restrict__ lists, float* __restrict__ wts)
{
  const int lane = threadIdx.x & 63;
  const int t = blockIdx.x * 4 + (threadIdx.x >> 6);
  float xv[8];
#pragma unroll
  for (int i = 0; i < 8; ++i) xv[i] = x[(size_t)t * DDIM + lane + 64 * i];
  float lg[8];
#pragma unroll
  for (int e = 0; e < 8; ++e) {
    float a = 0.f;
#pragma unroll
    for (int i = 0; i < 8; ++i) a += xv[i] * gw[e * DDIM + lane + 64 * i];
#pragma unroll
    for (int s = 32; s; s >>= 1) a += __shfl_xor(a, s, 64);
    lg[e] = a;
  }
  if (lane < 8) logits[(size_t)t * 8 + lane] = lg[lane];
  if (lane == 0) {
    // top-2, ties -> lower index (matches jax.lax.top_k)
    int i0 = 0; float v0 = lg[0];
#pragma unroll
    for (int e = 1; e < 8; ++e) { if (lg[e] > v0) { v0 = lg[e]; i0 = e; } }
    int i1 = -1; float v1 = -3.4e38f;
#pragma unroll
    for (int e = 0; e < 8; ++e) { if (e != i0 && lg[e] > v1) { v1 = lg[e]; i1 = e; } }
    float ex = expf(v1 - v0);            // v1 <= v0, no overflow
    float inv = 1.f / (1.f + ex);
    int p0 = atomicAdd(&counts[i0], 1);
    lists[i0 * TTOK + p0] = t; wts[i0 * TTOK + p0] = inv;
    int p1 = atomicAdd(&counts[i1], 1);
    lists[i1 * TTOK + p1] = t; wts[i1 * TTOK + p1] = ex * inv;
  }
}

__global__ void k_offsets(const int* __restrict__ counts, int* __restrict__ offs) {
  if (threadIdx.x == 0 && blockIdx.x == 0) {
    int s = 0;
    for (int e = 0; e < NEXP; ++e) { offs[e] = s; s += counts[e]; }
  }
}

// ---------------- GEMM1: H = silu(X W1^T) * (X W3^T), gathered rows, bf16 out
__global__ __launch_bounds__(512) void k_ffn1(
    const float* __restrict__ x, const float* __restrict__ w1,
    const float* __restrict__ w3, const int* __restrict__ counts,
    const int* __restrict__ offs, const int* __restrict__ lists,
    ushort* __restrict__ H)
{
  const int e = blockIdx.z;
  const int ne = counts[e];
  const int m0 = blockIdx.y * 128;
  if (m0 >= ne) return;
  const int f0 = blockIdx.x * 128;
  const int tid = threadIdx.x;

  __shared__ ushort xs[128][64];
  __shared__ ushort w1s[128][64];
  __shared__ ushort w3s[128][64];
  __shared__ int toks[128];

  if (tid < 128) {
    int p = m0 + tid;
    toks[tid] = (p < ne) ? lists[e * TTOK + p] : 0;
  }

  const int wid = tid >> 6, lane = tid & 63;
  const int wm = wid >> 2, wn = wid & 3;     // 2 x 4 wave grid
  const int lr = lane & 15, lgp = lane >> 4;

  floatx4 acc1[4][2], acc3[4][2];
#pragma unroll
  for (int a = 0; a < 4; ++a)
#pragma unroll
    for (int b = 0; b < 2; ++b) { acc1[a][b] = (floatx4)0.f; acc3[a][b] = (floatx4)0.f; }

  const size_t wbase = (size_t)e * FDIM * DDIM + (size_t)f0 * DDIM;

  for (int k0 = 0; k0 < DDIM; k0 += 64) {
    __syncthreads();
#pragma unroll
    for (int i = 0; i < 4; ++i) {
      int idx = tid + i * 512;          // 0..2047
      int row = idx >> 4;               // 0..127
      int c4 = (idx & 15) << 2;         // 0..60
      float4 xv = *(const float4*)&x[(size_t)toks[row] * DDIM + k0 + c4];
      ushort4 xb = { f2b(xv.x), f2b(xv.y), f2b(xv.z), f2b(xv.w) };
      *(ushort4*)&xs[row][c4] = xb;
      float4 av = *(const float4*)&w1[wbase + (size_t)row * DDIM + k0 + c4];
      ushort4 ab = { f2b(av.x), f2b(av.y), f2b(av.z), f2b(av.w) };
      *(ushort4*)&w1s[row][c4] = ab;
      float4 bv = *(const float4*)&w3[wbase + (size_t)row * DDIM + k0 + c4];
      ushort4 bb = { f2b(bv.x), f2b(bv.y), f2b(bv.z), f2b(bv.w) };
      *(ushort4*)&w3s[row][c4] = bb;
    }
    __syncthreads();
#pragma unroll
    for (int kk = 0; kk < 2; ++kk) {
      short8 afr[4], b1fr[2], b3fr[2];
#pragma unroll
      for (int mf = 0; mf < 4; ++mf)
        afr[mf] = *(const short8*)&xs[wm * 64 + mf * 16 + lr][kk * 32 + lgp * 8];
#pragma unroll
      for (int nf = 0; nf < 2; ++nf) {
        b1fr[nf] = *(const short8*)&w1s[wn * 32 + nf * 16 + lr][kk * 32 + lgp * 8];
        b3fr[nf] = *(const short8*)&w3s[wn * 32 + nf * 16 + lr][kk * 32 + lgp * 8];
      }
#pragma unroll
      for (int mf = 0; mf < 4; ++mf)
#pragma unroll
        for (int nf = 0; nf < 2; ++nf) {
          acc1[mf][nf] = __builtin_amdgcn_mfma_f32_16x16x32_bf16(afr[mf], b1fr[nf], acc1[mf][nf], 0, 0, 0);
          acc3[mf][nf] = __builtin_amdgcn_mfma_f32_16x16x32_bf16(afr[mf], b3fr[nf], acc3[mf][nf], 0, 0, 0);
        }
    }
  }

  const int hb = offs[e];
#pragma unroll
  for (int mf = 0; mf < 4; ++mf) {
#pragma unroll
    for (int j = 0; j < 4; ++j) {
      int rloc = wm * 64 + mf * 16 + lgp * 4 + j;   // C/D: row=(l>>4)*4+j
      int p = m0 + rloc;
      if (p < ne) {
#pragma unroll
        for (int nf = 0; nf < 2; ++nf) {
          float h1 = acc1[mf][nf][j];
          float h3 = acc3[mf][nf][j];
          float sig = 1.f / (1.f + __expf(-h1));
          int f = f0 + wn * 32 + nf * 16 + lr;      // C/D: col=l&15
          H[(size_t)(hb + p) * FDIM + f] = f2b(h1 * sig * h3);
        }
      }
    }
  }
}

// ---------------- GEMM2: Y = H W2^T, scaled atomic scatter into out
__global__ __launch_bounds__(512) void k_ffn2(
    const float* __restrict__ w2, const int* __restrict__ counts,
    const int* __restrict__ offs, const int* __restrict__ lists,
    const float* __restrict__ wts, const ushort* __restrict__ H,
    float* __restrict__ out)
{
  const int e = blockIdx.z;
  const int ne = counts[e];
  const int m0 = blockIdx.y * 128;
  if (m0 >= ne) return;
  const int d0 = blockIdx.x * 128;
  const int tid = threadIdx.x;

  __shared__ ushort hs[128][64];
  __shared__ ushort w2s[128][64];
  __shared__ int toks[128];
  __shared__ float twt[128];

  const int hb = offs[e];
  if (tid < 128) {
    int p = m0 + tid;
    bool v = p < ne;
    toks[tid] = v ? lists[e * TTOK + p] : 0;
    twt[tid] = v ? wts[e * TTOK + p] : 0.f;
  }

  const int wid = tid >> 6, lane = tid & 63;
  const int wm = wid >> 2, wn = wid & 3;
  const int lr = lane & 15, lgp = lane >> 4;

  floatx4 acc[4][2];
#pragma unroll
  for (int a = 0; a < 4; ++a)
#pragma unroll
    for (int b = 0; b < 2; ++b) acc[a][b] = (floatx4)0.f;

  const size_t wbase = (size_t)e * DDIM * FDIM + (size_t)d0 * FDIM;

  for (int k0 = 0; k0 < FDIM; k0 += 64) {
    __syncthreads();
#pragma unroll
    for (int i = 0; i < 2; ++i) {
      int idx = tid + i * 512;          // 0..1023
      int row = idx >> 3;               // 0..127
      int c8 = (idx & 7) << 3;          // 0..56
      int p = m0 + row;
      int hr = (p < ne) ? (hb + p) : hb;   // clamp to a valid row
      *(short8*)&hs[row][c8] = *(const short8*)&H[(size_t)hr * FDIM + k0 + c8];
    }
#pragma unroll
    for (int i = 0; i < 4; ++i) {
      int idx = tid + i * 512;
      int row = idx >> 4;
      int c4 = (idx & 15) << 2;
      float4 wv = *(const float4*)&w2[wbase + (size_t)row * FDIM + k0 + c4];
      ushort4 wb = { f2b(wv.x), f2b(wv.y), f2b(wv.z), f2b(wv.w) };
      *(ushort4*)&w2s[row][c4] = wb;
    }
    __syncthreads();
#pragma unroll
    for (int kk = 0; kk < 2; ++kk) {
      short8 afr[4], bfr[2];
#pragma unroll
      for (int mf = 0; mf < 4; ++mf)
        afr[mf] = *(const short8*)&hs[wm * 64 + mf * 16 + lr][kk * 32 + lgp * 8];
#pragma unroll
      for (int nf = 0; nf < 2; ++nf)
        bfr[nf] = *(const short8*)&w2s[wn * 32 + nf * 16 + lr][kk * 32 + lgp * 8];
#pragma unroll
      for (int mf = 0; mf < 4; ++mf)
#pragma unroll
        for (int nf = 0; nf < 2; ++nf)
          acc[mf][nf] = __builtin_amdgcn_mfma_f32_16x16x32_bf16(afr[mf], bfr[nf], acc[mf][nf], 0, 0, 0);
    }
  }

#pragma unroll
  for (int mf = 0; mf < 4; ++mf) {
#pragma unroll
    for (int j = 0; j < 4; ++j) {
      int rloc = wm * 64 + mf * 16 + lgp * 4 + j;
      int p = m0 + rloc;
      if (p < ne) {
        int t = toks[rloc];
        float w = twt[rloc];
#pragma unroll
        for (int nf = 0; nf < 2; ++nf) {
          int d = d0 + wn * 32 + nf * 16 + lr;
          atomicAdd(&out[(size_t)t * DDIM + d], w * acc[mf][nf][j]);
        }
      }
    }
  }
}

extern "C" void kernel_launch(void* const* d_in, const int* in_sizes, int n_in,
                              void* d_out, int out_size, void* d_ws, size_t ws_size,
                              hipStream_t stream) {
  const float* x  = (const float*)d_in[0];
  const float* gw = (const float*)d_in[1];
  const float* w1 = (const float*)d_in[2];
  const float* w2 = (const float*)d_in[3];
  const float* w3 = (const float*)d_in[4];
  float* out = (float*)d_out;
  float* logits = out + (size_t)TTOK * DDIM;

  // workspace layout (needs ~33.8 MB):
  int* counts = (int*)d_ws;                       // [8]
  int* offs   = counts + 8;                       // [8]
  int* lists  = offs + 8;                         // [8][4096]
  float* wts  = (float*)(lists + NEXP * TTOK);    // [8][4096]
  ushort* H   = (ushort*)(wts + NEXP * TTOK);     // [8192][2048] bf16

  hipMemsetAsync(counts, 0, 8 * sizeof(int), stream);
  hipMemsetAsync(d_out, 0, (size_t)TTOK * DDIM * sizeof(float), stream);

  k_router<<<TTOK / 4, 256, 0, stream>>>(x, gw, logits, counts, lists, wts);
  k_offsets<<<1, 64, 0, stream>>>(counts, offs);
  k_ffn1<<<dim3(FDIM / 128, TTOK / 128, NEXP), 512, 0, stream>>>(x, w1, w3, counts, offs, lists, H);
  k_ffn2<<<dim3(DDIM / 128, TTOK / 128, NEXP), 512, 0, stream>>>(w2, counts, offs, lists, wts, H, out);
}

// Round 2
// 270.583 us; speedup vs baseline: 1.2230x; 1.2230x over previous
//
#include <hip/hip_runtime.h>

#define TTOK 4096
#define NEXP 8
#define DDIM 512
#define FDIM 2048

typedef __attribute__((ext_vector_type(8))) short short8;
typedef __attribute__((ext_vector_type(4))) float floatx4;

__device__ __forceinline__ ushort f2b(float f) {
  unsigned u = __float_as_uint(f);
  u += 0x7fffu + ((u >> 16) & 1u);   // round-to-nearest-even bf16
  return (ushort)(u >> 16);
}

__device__ __forceinline__ void load16(void* lds, const void* g) {
  __builtin_amdgcn_global_load_lds(
      (const __attribute__((address_space(1))) unsigned int*)g,
      (__attribute__((address_space(3))) unsigned int*)lds, 16, 0, 0);
}

// ---------------- f32 -> bf16 bulk convert (float4 -> ushort4)
__global__ __launch_bounds__(256) void k_cvt(
    const float* __restrict__ src, ushort* __restrict__ dst, int n4)
{
  int i = blockIdx.x * 256 + threadIdx.x;
  if (i < n4) {
    float4 v = ((const float4*)src)[i];
    ushort4 b = { f2b(v.x), f2b(v.y), f2b(v.z), f2b(v.w) };
    ((ushort4*)dst)[i] = b;
  }
}

// ---------------- router: logits (f32, exact) + top-2 + softmax + list append
__global__ __launch_bounds__(256) void k_router(
    const float* __restrict__ x, const float* __restrict__ gw,
    float* __restrict__ logits, int* __restrict__ counts,
    int* __restrict__ lists, float* __restrict__ wts)
{
  const int lane = threadIdx.x & 63;
  const int t = blockIdx.x * 4 + (threadIdx.x >> 6);
  float xv[8];
#pragma unroll
  for (int i = 0; i < 8; ++i) xv[i] = x[(size_t)t * DDIM + lane + 64 * i];
  float lg[8];
#pragma unroll
  for (int e = 0; e < 8; ++e) {
    float a = 0.f;
#pragma unroll
    for (int i = 0; i < 8; ++i) a += xv[i] * gw[e * DDIM + lane + 64 * i];
#pragma unroll
    for (int s = 32; s; s >>= 1) a += __shfl_xor(a, s, 64);
    lg[e] = a;
  }
  if (lane < 8) logits[(size_t)t * 8 + lane] = lg[lane];
  if (lane == 0) {
    int i0 = 0; float v0 = lg[0];
#pragma unroll
    for (int e = 1; e < 8; ++e) { if (lg[e] > v0) { v0 = lg[e]; i0 = e; } }
    int i1 = -1; float v1 = -3.4e38f;
#pragma unroll
    for (int e = 0; e < 8; ++e) { if (e != i0 && lg[e] > v1) { v1 = lg[e]; i1 = e; } }
    float ex = expf(v1 - v0);
    float inv = 1.f / (1.f + ex);
    int p0 = atomicAdd(&counts[i0], 1);
    lists[i0 * TTOK + p0] = t; wts[i0 * TTOK + p0] = inv;
    int p1 = atomicAdd(&counts[i1], 1);
    lists[i1 * TTOK + p1] = t; wts[i1 * TTOK + p1] = ex * inv;
  }
}

__global__ void k_offsets(const int* __restrict__ counts, int* __restrict__ offs) {
  if (threadIdx.x == 0 && blockIdx.x == 0) {
    int s = 0;
    for (int e = 0; e < NEXP; ++e) { offs[e] = s; s += counts[e]; }
  }
}

// ---------------- GEMM1: H = silu(X W1^T) * (X W3^T), bf16 in/out, gload_lds staging
__global__ __launch_bounds__(512) void k_ffn1(
    const ushort* __restrict__ xb, const ushort* __restrict__ w1b,
    const ushort* __restrict__ w3b, const int* __restrict__ counts,
    const int* __restrict__ offs, const int* __restrict__ lists,
    ushort* __restrict__ H)
{
  const int e = blockIdx.z;
  const int ne = counts[e];
  const int m0 = blockIdx.y * 128;
  if (m0 >= ne) return;
  const int f0 = blockIdx.x * 128;
  const int tid = threadIdx.x;

  __shared__ ushort xs[128][64];
  __shared__ ushort w1s[128][64];
  __shared__ ushort w3s[128][64];
  __shared__ int toks[128];

  if (tid < 128) {
    int p = m0 + tid;
    toks[tid] = (p < ne) ? lists[e * TTOK + p] : 0;
  }
  __syncthreads();

  const int wid = tid >> 6, lane = tid & 63;
  const int wm = wid >> 2, wn = wid & 3;     // 2 x 4 wave grid
  const int lr = lane & 15, lgp = lane >> 4;

  // staging geometry: idx in [0,1024), 16B each; row = idx>>3, col = (idx&7)*8
  const int idxA = tid, idxB = tid + 512;
  const int rA = idxA >> 3, cA = (idxA & 7) << 3;
  const int rB = idxB >> 3, cB = (idxB & 7) << 3;
  const size_t wroff = (size_t)e * FDIM * DDIM + (size_t)f0 * DDIM;

  const ushort* xA  = xb + (size_t)toks[rA] * DDIM + cA;
  const ushort* xB  = xb + (size_t)toks[rB] * DDIM + cB;
  const ushort* w1A = w1b + wroff + (size_t)rA * DDIM + cA;
  const ushort* w1B = w1b + wroff + (size_t)rB * DDIM + cB;
  const ushort* w3A = w3b + wroff + (size_t)rA * DDIM + cA;
  const ushort* w3B = w3b + wroff + (size_t)rB * DDIM + cB;

  char* xdA  = (char*)xs  + wid * 1024;  char* xdB  = xdA  + 8192;
  char* w1dA = (char*)w1s + wid * 1024;  char* w1dB = w1dA + 8192;
  char* w3dA = (char*)w3s + wid * 1024;  char* w3dB = w3dA + 8192;

  floatx4 acc1[4][2], acc3[4][2];
#pragma unroll
  for (int a = 0; a < 4; ++a)
#pragma unroll
    for (int b = 0; b < 2; ++b) { acc1[a][b] = (floatx4)0.f; acc3[a][b] = (floatx4)0.f; }

  for (int k0 = 0; k0 < DDIM; k0 += 64) {
    __syncthreads();
    load16(xdA, xA);   load16(xdB, xB);
    load16(w1dA, w1A); load16(w1dB, w1B);
    load16(w3dA, w3A); load16(w3dB, w3B);
    xA += 64; xB += 64; w1A += 64; w1B += 64; w3A += 64; w3B += 64;
    __syncthreads();
#pragma unroll
    for (int kk = 0; kk < 2; ++kk) {
      short8 afr[4], b1fr[2], b3fr[2];
#pragma unroll
      for (int mf = 0; mf < 4; ++mf)
        afr[mf] = *(const short8*)&xs[wm * 64 + mf * 16 + lr][kk * 32 + lgp * 8];
#pragma unroll
      for (int nf = 0; nf < 2; ++nf) {
        b1fr[nf] = *(const short8*)&w1s[wn * 32 + nf * 16 + lr][kk * 32 + lgp * 8];
        b3fr[nf] = *(const short8*)&w3s[wn * 32 + nf * 16 + lr][kk * 32 + lgp * 8];
      }
#pragma unroll
      for (int mf = 0; mf < 4; ++mf)
#pragma unroll
        for (int nf = 0; nf < 2; ++nf) {
          acc1[mf][nf] = __builtin_amdgcn_mfma_f32_16x16x32_bf16(afr[mf], b1fr[nf], acc1[mf][nf], 0, 0, 0);
          acc3[mf][nf] = __builtin_amdgcn_mfma_f32_16x16x32_bf16(afr[mf], b3fr[nf], acc3[mf][nf], 0, 0, 0);
        }
    }
  }

  const int hb = offs[e];
#pragma unroll
  for (int mf = 0; mf < 4; ++mf) {
#pragma unroll
    for (int j = 0; j < 4; ++j) {
      int rloc = wm * 64 + mf * 16 + lgp * 4 + j;   // C/D: row=(l>>4)*4+j
      int p = m0 + rloc;
      if (p < ne) {
#pragma unroll
        for (int nf = 0; nf < 2; ++nf) {
          float h1 = acc1[mf][nf][j];
          float h3 = acc3[mf][nf][j];
          float sig = 1.f / (1.f + __expf(-h1));
          int f = f0 + wn * 32 + nf * 16 + lr;      // C/D: col=l&15
          H[(size_t)(hb + p) * FDIM + f] = f2b(h1 * sig * h3);
        }
      }
    }
  }
}

// ---------------- GEMM2: Y = H W2^T, scaled atomic scatter into out
__global__ __launch_bounds__(512) void k_ffn2(
    const ushort* __restrict__ w2b, const int* __restrict__ counts,
    const int* __restrict__ offs, const int* __restrict__ lists,
    const float* __restrict__ wts, const ushort* __restrict__ H,
    float* __restrict__ out)
{
  const int e = blockIdx.z;
  const int ne = counts[e];
  const int m0 = blockIdx.y * 128;
  if (m0 >= ne) return;
  const int d0 = blockIdx.x * 128;
  const int tid = threadIdx.x;

  __shared__ ushort hs[128][64];
  __shared__ ushort w2s[128][64];
  __shared__ int toks[128];
  __shared__ float twt[128];

  const int hb = offs[e];
  if (tid < 128) {
    int p = m0 + tid;
    bool v = p < ne;
    toks[tid] = v ? lists[e * TTOK + p] : 0;
    twt[tid] = v ? wts[e * TTOK + p] : 0.f;
  }

  const int wid = tid >> 6, lane = tid & 63;
  const int wm = wid >> 2, wn = wid & 3;
  const int lr = lane & 15, lgp = lane >> 4;

  const int idxA = tid, idxB = tid + 512;
  const int rA = idxA >> 3, cA = (idxA & 7) << 3;
  const int rB = idxB >> 3, cB = (idxB & 7) << 3;
  const int pA = m0 + rA, pB = m0 + rB;
  const int hrA = (pA < ne) ? (hb + pA) : hb;
  const int hrB = (pB < ne) ? (hb + pB) : hb;
  const size_t wroff = (size_t)e * DDIM * FDIM + (size_t)d0 * FDIM;

  const ushort* hA  = H + (size_t)hrA * FDIM + cA;
  const ushort* hB  = H + (size_t)hrB * FDIM + cB;
  const ushort* w2A = w2b + wroff + (size_t)rA * FDIM + cA;
  const ushort* w2B = w2b + wroff + (size_t)rB * FDIM + cB;

  char* hdA  = (char*)hs  + wid * 1024;  char* hdB  = hdA  + 8192;
  char* w2dA = (char*)w2s + wid * 1024;  char* w2dB = w2dA + 8192;

  floatx4 acc[4][2];
#pragma unroll
  for (int a = 0; a < 4; ++a)
#pragma unroll
    for (int b = 0; b < 2; ++b) acc[a][b] = (floatx4)0.f;

  for (int k0 = 0; k0 < FDIM; k0 += 64) {
    __syncthreads();
    load16(hdA, hA);   load16(hdB, hB);
    load16(w2dA, w2A); load16(w2dB, w2B);
    hA += 64; hB += 64; w2A += 64; w2B += 64;
    __syncthreads();
#pragma unroll
    for (int kk = 0; kk < 2; ++kk) {
      short8 afr[4], bfr[2];
#pragma unroll
      for (int mf = 0; mf < 4; ++mf)
        afr[mf] = *(const short8*)&hs[wm * 64 + mf * 16 + lr][kk * 32 + lgp * 8];
#pragma unroll
      for (int nf = 0; nf < 2; ++nf)
        bfr[nf] = *(const short8*)&w2s[wn * 32 + nf * 16 + lr][kk * 32 + lgp * 8];
#pragma unroll
      for (int mf = 0; mf < 4; ++mf)
#pragma unroll
        for (int nf = 0; nf < 2; ++nf)
          acc[mf][nf] = __builtin_amdgcn_mfma_f32_16x16x32_bf16(afr[mf], bfr[nf], acc[mf][nf], 0, 0, 0);
    }
  }

#pragma unroll
  for (int mf = 0; mf < 4; ++mf) {
#pragma unroll
    for (int j = 0; j < 4; ++j) {
      int rloc = wm * 64 + mf * 16 + lgp * 4 + j;
      int p = m0 + rloc;
      if (p < ne) {
        int t = toks[rloc];
        float w = twt[rloc];
#pragma unroll
        for (int nf = 0; nf < 2; ++nf) {
          int d = d0 + wn * 32 + nf * 16 + lr;
          atomicAdd(&out[(size_t)t * DDIM + d], w * acc[mf][nf][j]);
        }
      }
    }
  }
}

extern "C" void kernel_launch(void* const* d_in, const int* in_sizes, int n_in,
                              void* d_out, int out_size, void* d_ws, size_t ws_size,
                              hipStream_t stream) {
  const float* x  = (const float*)d_in[0];
  const float* gw = (const float*)d_in[1];
  const float* w1 = (const float*)d_in[2];
  const float* w2 = (const float*)d_in[3];
  const float* w3 = (const float*)d_in[4];
  float* out = (float*)d_out;
  float* logits = out + (size_t)TTOK * DDIM;

  // workspace layout (~88.2 MB)
  int* counts = (int*)d_ws;                       // [8]
  int* offs   = counts + 8;                       // [8]
  int* lists  = offs + 8;                         // [8][4096]
  float* wts  = (float*)(lists + NEXP * TTOK);    // [8][4096]
  ushort* xbb = (ushort*)(wts + NEXP * TTOK);     // [4096][512]  bf16
  ushort* w1b = xbb + (size_t)TTOK * DDIM;        // [8][2048][512] bf16
  ushort* w3b = w1b + (size_t)NEXP * FDIM * DDIM;
  ushort* w2b = w3b + (size_t)NEXP * FDIM * DDIM; // [8][512][2048] bf16
  ushort* H   = w2b + (size_t)NEXP * DDIM * FDIM; // [8192][2048] bf16

  hipMemsetAsync(counts, 0, 8 * sizeof(int), stream);
  hipMemsetAsync(d_out, 0, (size_t)TTOK * DDIM * sizeof(float), stream);

  const int nW = NEXP * FDIM * DDIM / 4;          // 2,097,152
  k_cvt<<<(TTOK * DDIM / 4 + 255) / 256, 256, 0, stream>>>(x, xbb, TTOK * DDIM / 4);
  k_cvt<<<(nW + 255) / 256, 256, 0, stream>>>(w1, w1b, nW);
  k_cvt<<<(nW + 255) / 256, 256, 0, stream>>>(w3, w3b, nW);
  k_cvt<<<(nW + 255) / 256, 256, 0, stream>>>(w2, w2b, nW);

  k_router<<<TTOK / 4, 256, 0, stream>>>(x, gw, logits, counts, lists, wts);
  k_offsets<<<1, 64, 0, stream>>>(counts, offs);
  k_ffn1<<<dim3(FDIM / 128, TTOK / 128, NEXP), 512, 0, stream>>>(xbb, w1b, w3b, counts, offs, lists, H);
  k_ffn2<<<dim3(DDIM / 128, TTOK / 128, NEXP), 512, 0, stream>>>(w2b, counts, offs, lists, wts, H, out);
}

// Round 3
// 188.215 us; speedup vs baseline: 1.7583x; 1.4376x over previous
//
#include <hip/hip_runtime.h>

#define TTOK 4096
#define NEXP 8
#define DDIM 512
#define FDIM 2048

typedef __attribute__((ext_vector_type(8))) short short8;
typedef __attribute__((ext_vector_type(4))) float floatx4;

__device__ __forceinline__ ushort f2b(float f) {
  unsigned u = __float_as_uint(f);
  u += 0x7fffu + ((u >> 16) & 1u);   // round-to-nearest-even bf16
  return (ushort)(u >> 16);
}

__device__ __forceinline__ void load16(void* lds, const void* g) {
  __builtin_amdgcn_global_load_lds(
      (const __attribute__((address_space(1))) unsigned int*)g,
      (__attribute__((address_space(3))) unsigned int*)lds, 16, 0, 0);
}

// ---------------- f32 -> bf16 bulk convert (float4 -> ushort4)
__global__ __launch_bounds__(256) void k_cvt(
    const float* __restrict__ src, ushort* __restrict__ dst, int n4)
{
  int i = blockIdx.x * 256 + threadIdx.x;
  if (i < n4) {
    float4 v = ((const float4*)src)[i];
    ushort4 b = { f2b(v.x), f2b(v.y), f2b(v.z), f2b(v.w) };
    ((ushort4*)dst)[i] = b;
  }
}

// ---------------- router pass 1: logits + per-token top-2 (NO atomics)
__global__ __launch_bounds__(256) void k_logits(
    const float* __restrict__ x, const float* __restrict__ gw,
    float* __restrict__ logits, int* __restrict__ tok_e,
    float2* __restrict__ tok_w)
{
  const int lane = threadIdx.x & 63;
  const int t = blockIdx.x * 4 + (threadIdx.x >> 6);
  float xv[8];
#pragma unroll
  for (int i = 0; i < 8; ++i) xv[i] = x[(size_t)t * DDIM + lane + 64 * i];
  float lg[8];
#pragma unroll
  for (int e = 0; e < 8; ++e) {
    float a = 0.f;
#pragma unroll
    for (int i = 0; i < 8; ++i) a += xv[i] * gw[e * DDIM + lane + 64 * i];
#pragma unroll
    for (int s = 32; s; s >>= 1) a += __shfl_xor(a, s, 64);
    lg[e] = a;
  }
  if (lane < 8) logits[(size_t)t * 8 + lane] = lg[lane];
  if (lane == 0) {
    // top-2, ties -> lower index (matches jax.lax.top_k)
    int i0 = 0; float v0 = lg[0];
#pragma unroll
    for (int e = 1; e < 8; ++e) { if (lg[e] > v0) { v0 = lg[e]; i0 = e; } }
    int i1 = -1; float v1 = -3.4e38f;
#pragma unroll
    for (int e = 0; e < 8; ++e) { if (e != i0 && lg[e] > v1) { v1 = lg[e]; i1 = e; } }
    float ex = expf(v1 - v0);            // v1 <= v0, no overflow
    float inv = 1.f / (1.f + ex);
    tok_e[t] = i0 | (i1 << 4);
    tok_w[t] = make_float2(inv, ex * inv);
  }
}

// ---------------- router pass 2: per-expert compaction, ballot prefix, no atomics
__global__ __launch_bounds__(256) void k_build(
    const int* __restrict__ tok_e, const float2* __restrict__ tok_w,
    int* __restrict__ counts, int* __restrict__ lists, float* __restrict__ wts)
{
  const int e = blockIdx.x;
  const int tid = threadIdx.x;
  const int lane = tid & 63, wid = tid >> 6;
  __shared__ int wcnt[4];
  __shared__ int sbase;
  if (tid == 0) sbase = 0;
  __syncthreads();

  for (int c = 0; c < TTOK; c += 256) {
    int t = c + tid;
    int pe = tok_e[t];
    bool m0 = (pe & 15) == e;
    bool m1 = ((pe >> 4) & 15) == e;
    bool m = m0 || m1;
    unsigned long long b = __ballot(m);
    int lpre = __popcll(b & ((1ull << lane) - 1ull));
    if (lane == 0) wcnt[wid] = __popcll(b);
    __syncthreads();
    int woff = 0;
#pragma unroll
    for (int i = 0; i < 4; ++i) if (i < wid) woff += wcnt[i];
    if (m) {
      float2 w = tok_w[t];
      int pos = sbase + woff + lpre;
      lists[e * TTOK + pos] = t;
      wts[e * TTOK + pos] = m0 ? w.x : w.y;
    }
    __syncthreads();
    if (tid == 0) sbase += wcnt[0] + wcnt[1] + wcnt[2] + wcnt[3];
    __syncthreads();
  }
  if (tid == 0) counts[e] = sbase;
}

__global__ void k_offsets(const int* __restrict__ counts, int* __restrict__ offs) {
  if (threadIdx.x == 0 && blockIdx.x == 0) {
    int s = 0;
    for (int e = 0; e < NEXP; ++e) { offs[e] = s; s += counts[e]; }
  }
}

// ---------------- GEMM1: H = silu(X W1^T) * (X W3^T), bf16 in/out, gload_lds staging
__global__ __launch_bounds__(512) void k_ffn1(
    const ushort* __restrict__ xb, const ushort* __restrict__ w1b,
    const ushort* __restrict__ w3b, const int* __restrict__ counts,
    const int* __restrict__ offs, const int* __restrict__ lists,
    ushort* __restrict__ H)
{
  const int e = blockIdx.z;
  const int ne = counts[e];
  const int m0 = blockIdx.y * 128;
  if (m0 >= ne) return;
  const int f0 = blockIdx.x * 128;
  const int tid = threadIdx.x;

  __shared__ ushort xs[128][64];
  __shared__ ushort w1s[128][64];
  __shared__ ushort w3s[128][64];
  __shared__ int toks[128];

  if (tid < 128) {
    int p = m0 + tid;
    toks[tid] = (p < ne) ? lists[e * TTOK + p] : 0;
  }
  __syncthreads();

  const int wid = tid >> 6, lane = tid & 63;
  const int wm = wid >> 2, wn = wid & 3;     // 2 x 4 wave grid
  const int lr = lane & 15, lgp = lane >> 4;

  const int idxA = tid, idxB = tid + 512;
  const int rA = idxA >> 3, cA = (idxA & 7) << 3;
  const int rB = idxB >> 3, cB = (idxB & 7) << 3;
  const size_t wroff = (size_t)e * FDIM * DDIM + (size_t)f0 * DDIM;

  const ushort* xA  = xb + (size_t)toks[rA] * DDIM + cA;
  const ushort* xB  = xb + (size_t)toks[rB] * DDIM + cB;
  const ushort* w1A = w1b + wroff + (size_t)rA * DDIM + cA;
  const ushort* w1B = w1b + wroff + (size_t)rB * DDIM + cB;
  const ushort* w3A = w3b + wroff + (size_t)rA * DDIM + cA;
  const ushort* w3B = w3b + wroff + (size_t)rB * DDIM + cB;

  char* xdA  = (char*)xs  + wid * 1024;  char* xdB  = xdA  + 8192;
  char* w1dA = (char*)w1s + wid * 1024;  char* w1dB = w1dA + 8192;
  char* w3dA = (char*)w3s + wid * 1024;  char* w3dB = w3dA + 8192;

  floatx4 acc1[4][2], acc3[4][2];
#pragma unroll
  for (int a = 0; a < 4; ++a)
#pragma unroll
    for (int b = 0; b < 2; ++b) { acc1[a][b] = (floatx4)0.f; acc3[a][b] = (floatx4)0.f; }

  for (int k0 = 0; k0 < DDIM; k0 += 64) {
    __syncthreads();
    load16(xdA, xA);   load16(xdB, xB);
    load16(w1dA, w1A); load16(w1dB, w1B);
    load16(w3dA, w3A); load16(w3dB, w3B);
    xA += 64; xB += 64; w1A += 64; w1B += 64; w3A += 64; w3B += 64;
    __syncthreads();
#pragma unroll
    for (int kk = 0; kk < 2; ++kk) {
      short8 afr[4], b1fr[2], b3fr[2];
#pragma unroll
      for (int mf = 0; mf < 4; ++mf)
        afr[mf] = *(const short8*)&xs[wm * 64 + mf * 16 + lr][kk * 32 + lgp * 8];
#pragma unroll
      for (int nf = 0; nf < 2; ++nf) {
        b1fr[nf] = *(const short8*)&w1s[wn * 32 + nf * 16 + lr][kk * 32 + lgp * 8];
        b3fr[nf] = *(const short8*)&w3s[wn * 32 + nf * 16 + lr][kk * 32 + lgp * 8];
      }
#pragma unroll
      for (int mf = 0; mf < 4; ++mf)
#pragma unroll
        for (int nf = 0; nf < 2; ++nf) {
          acc1[mf][nf] = __builtin_amdgcn_mfma_f32_16x16x32_bf16(afr[mf], b1fr[nf], acc1[mf][nf], 0, 0, 0);
          acc3[mf][nf] = __builtin_amdgcn_mfma_f32_16x16x32_bf16(afr[mf], b3fr[nf], acc3[mf][nf], 0, 0, 0);
        }
    }
  }

  const int hb = offs[e];
#pragma unroll
  for (int mf = 0; mf < 4; ++mf) {
#pragma unroll
    for (int j = 0; j < 4; ++j) {
      int rloc = wm * 64 + mf * 16 + lgp * 4 + j;   // C/D: row=(l>>4)*4+j
      int p = m0 + rloc;
      if (p < ne) {
#pragma unroll
        for (int nf = 0; nf < 2; ++nf) {
          float h1 = acc1[mf][nf][j];
          float h3 = acc3[mf][nf][j];
          float sig = 1.f / (1.f + __expf(-h1));
          int f = f0 + wn * 32 + nf * 16 + lr;      // C/D: col=l&15
          H[(size_t)(hb + p) * FDIM + f] = f2b(h1 * sig * h3);
        }
      }
    }
  }
}

// ---------------- GEMM2: Y = H W2^T, scaled atomic scatter into out
__global__ __launch_bounds__(512) void k_ffn2(
    const ushort* __restrict__ w2b, const int* __restrict__ counts,
    const int* __restrict__ offs, const int* __restrict__ lists,
    const float* __restrict__ wts, const ushort* __restrict__ H,
    float* __restrict__ out)
{
  const int e = blockIdx.z;
  const int ne = counts[e];
  const int m0 = blockIdx.y * 128;
  if (m0 >= ne) return;
  const int d0 = blockIdx.x * 128;
  const int tid = threadIdx.x;

  __shared__ ushort hs[128][64];
  __shared__ ushort w2s[128][64];
  __shared__ int toks[128];
  __shared__ float twt[128];

  const int hb = offs[e];
  if (tid < 128) {
    int p = m0 + tid;
    bool v = p < ne;
    toks[tid] = v ? lists[e * TTOK + p] : 0;
    twt[tid] = v ? wts[e * TTOK + p] : 0.f;
  }
  __syncthreads();

  const int wid = tid >> 6, lane = tid & 63;
  const int wm = wid >> 2, wn = wid & 3;
  const int lr = lane & 15, lgp = lane >> 4;

  const int idxA = tid, idxB = tid + 512;
  const int rA = idxA >> 3, cA = (idxA & 7) << 3;
  const int rB = idxB >> 3, cB = (idxB & 7) << 3;
  const int pA = m0 + rA, pB = m0 + rB;
  const int hrA = (pA < ne) ? (hb + pA) : hb;
  const int hrB = (pB < ne) ? (hb + pB) : hb;
  const size_t wroff = (size_t)e * DDIM * FDIM + (size_t)d0 * FDIM;

  const ushort* hA  = H + (size_t)hrA * FDIM + cA;
  const ushort* hB  = H + (size_t)hrB * FDIM + cB;
  const ushort* w2A = w2b + wroff + (size_t)rA * FDIM + cA;
  const ushort* w2B = w2b + wroff + (size_t)rB * FDIM + cB;

  char* hdA  = (char*)hs  + wid * 1024;  char* hdB  = hdA  + 8192;
  char* w2dA = (char*)w2s + wid * 1024;  char* w2dB = w2dA + 8192;

  floatx4 acc[4][2];
#pragma unroll
  for (int a = 0; a < 4; ++a)
#pragma unroll
    for (int b = 0; b < 2; ++b) acc[a][b] = (floatx4)0.f;

  for (int k0 = 0; k0 < FDIM; k0 += 64) {
    __syncthreads();
    load16(hdA, hA);   load16(hdB, hB);
    load16(w2dA, w2A); load16(w2dB, w2B);
    hA += 64; hB += 64; w2A += 64; w2B += 64;
    __syncthreads();
#pragma unroll
    for (int kk = 0; kk < 2; ++kk) {
      short8 afr[4], bfr[2];
#pragma unroll
      for (int mf = 0; mf < 4; ++mf)
        afr[mf] = *(const short8*)&hs[wm * 64 + mf * 16 + lr][kk * 32 + lgp * 8];
#pragma unroll
      for (int nf = 0; nf < 2; ++nf)
        bfr[nf] = *(const short8*)&w2s[wn * 32 + nf * 16 + lr][kk * 32 + lgp * 8];
#pragma unroll
      for (int mf = 0; mf < 4; ++mf)
#pragma unroll
        for (int nf = 0; nf < 2; ++nf)
          acc[mf][nf] = __builtin_amdgcn_mfma_f32_16x16x32_bf16(afr[mf], bfr[nf], acc[mf][nf], 0, 0, 0);
    }
  }

#pragma unroll
  for (int mf = 0; mf < 4; ++mf) {
#pragma unroll
    for (int j = 0; j < 4; ++j) {
      int rloc = wm * 64 + mf * 16 + lgp * 4 + j;
      int p = m0 + rloc;
      if (p < ne) {
        int t = toks[rloc];
        float w = twt[rloc];
#pragma unroll
        for (int nf = 0; nf < 2; ++nf) {
          int d = d0 + wn * 32 + nf * 16 + lr;
          atomicAdd(&out[(size_t)t * DDIM + d], w * acc[mf][nf][j]);
        }
      }
    }
  }
}

extern "C" void kernel_launch(void* const* d_in, const int* in_sizes, int n_in,
                              void* d_out, int out_size, void* d_ws, size_t ws_size,
                              hipStream_t stream) {
  const float* x  = (const float*)d_in[0];
  const float* gw = (const float*)d_in[1];
  const float* w1 = (const float*)d_in[2];
  const float* w2 = (const float*)d_in[3];
  const float* w3 = (const float*)d_in[4];
  float* out = (float*)d_out;
  float* logits = out + (size_t)TTOK * DDIM;

  // workspace layout (~88.3 MB)
  int* counts = (int*)d_ws;                       // [8]
  int* offs   = counts + 8;                       // [8]
  int* tok_e  = offs + 8;                         // [4096]
  float2* tok_w = (float2*)(tok_e + TTOK);        // [4096]
  int* lists  = (int*)(tok_w + TTOK);             // [8][4096]
  float* wts  = (float*)(lists + NEXP * TTOK);    // [8][4096]
  ushort* xbb = (ushort*)(wts + NEXP * TTOK);     // [4096][512]  bf16
  ushort* w1b = xbb + (size_t)TTOK * DDIM;        // [8][2048][512] bf16
  ushort* w3b = w1b + (size_t)NEXP * FDIM * DDIM;
  ushort* w2b = w3b + (size_t)NEXP * FDIM * DDIM; // [8][512][2048] bf16
  ushort* H   = w2b + (size_t)NEXP * DDIM * FDIM; // [8192][2048] bf16

  hipMemsetAsync(d_out, 0, (size_t)TTOK * DDIM * sizeof(float), stream);

  const int nW = NEXP * FDIM * DDIM / 4;          // 2,097,152
  k_logits<<<TTOK / 4, 256, 0, stream>>>(x, gw, logits, tok_e, tok_w);
  k_build<<<NEXP, 256, 0, stream>>>(tok_e, tok_w, counts, lists, wts);
  k_offsets<<<1, 64, 0, stream>>>(counts, offs);

  k_cvt<<<(TTOK * DDIM / 4 + 255) / 256, 256, 0, stream>>>(x, xbb, TTOK * DDIM / 4);
  k_cvt<<<(nW + 255) / 256, 256, 0, stream>>>(w1, w1b, nW);
  k_cvt<<<(nW + 255) / 256, 256, 0, stream>>>(w3, w3b, nW);
  k_cvt<<<(nW + 255) / 256, 256, 0, stream>>>(w2, w2b, nW);

  k_ffn1<<<dim3(FDIM / 128, TTOK / 128, NEXP), 512, 0, stream>>>(xbb, w1b, w3b, counts, offs, lists, H);
  k_ffn2<<<dim3(DDIM / 128, TTOK / 128, NEXP), 512, 0, stream>>>(w2b, counts, offs, lists, wts, H, out);
}